// Round 7
// baseline (1614.957 us; speedup 1.0000x reference)
//
#include <hip/hip_runtime.h>

// ---------------------------------------------------------------------------
// MusicLSTM: B=256, T=2048, I=2, H=128 (4H=512 gates), P=129 pitches.
//   prep_k  : note_W+dur_W -> f16 Wn[144][128] in ws
//   lstm2_k : 32 WGs x 8 batches, 512 thr (8 waves). Per step one MFMA GEMM
//             gates[16x512] = h[16x128] . W_hh^T  (A rows = 8 batches x2
//             replicated). Wave w owns N-tiles {w,w+8,w+16,w+24} so i,f,g,o
//             for a (batch, col j) all land in ONE lane's acc regs -> no
//             cross-lane gather. 2 cell updates/lane, c/h in regs, h fed back
//             through double-buffered padded LDS. Raw s_barrier with
//             lgkm-only wait (global hs stores stay in flight). x staged in
//             LDS in 128-step chunks.
//   proj_k  : MFMA f16 GEMM over hs -> note/dur logits, masked rows zeroed.
// Fragment layout conventions (verified by the passing proj_k):
//   A: lane l holds A[m=l&15][k=32*kt+8*(l>>4)+e], e=0..7
//   B: lane l holds B[n=l&15][k=...same]
//   D: lane l reg r holds D[m=(l>>4)*4+r][n=l&15]
// ---------------------------------------------------------------------------

typedef _Float16 f16;
typedef _Float16 f16x8 __attribute__((ext_vector_type(8)));
typedef float    f32x4 __attribute__((ext_vector_type(4)));

#define B_  256
#define T_  2048
#define H_  128
#define P_  129

static constexpr size_t NOTE_N   = (size_t)B_ * T_ * P_;
static constexpr size_t DUR_BASE = NOTE_N;
static constexpr size_t HT_BASE  = DUR_BASE + (size_t)B_ * T_;
static constexpr size_t CT_BASE  = HT_BASE + (size_t)B_ * H_;

#if defined(__has_builtin)
#if __has_builtin(__builtin_amdgcn_exp2f)
#define EXP2F(x) __builtin_amdgcn_exp2f(x)
#endif
#endif
#ifndef EXP2F
#define EXP2F(x) __expf((x) * 0.6931471805599453f)
#endif

__device__ __forceinline__ float fast_rcp(float x) { return __builtin_amdgcn_rcpf(x); }

__device__ __forceinline__ float sigmoid_f(float x) {
    float e = EXP2F(-1.44269504f * x);
    return fast_rcp(1.f + e);
}
__device__ __forceinline__ float tanh_f(float x) {
    float e = EXP2F(2.885390082f * x);
    return (e - 1.f) * fast_rcp(e + 1.f);
}

// hs row bt lives at the front of note row bt, rounded up to 16B alignment.
__device__ __forceinline__ f16* hs_row(float* out, int bt) {
    size_t byteoff = ((size_t)bt * (P_ * 4) + 15) & ~(size_t)15;
    return (f16*)((char*)out + byteoff);
}

// ---------------------------------------------------------------------------
__global__ __launch_bounds__(256) void prep_k(const float* __restrict__ note_W,
                                              const float* __restrict__ dur_W,
                                              f16* __restrict__ Wn) {
    int i = threadIdx.x + blockIdx.x * 256;
    if (i >= 144 * 128) return;
    int row = i >> 7, k = i & 127;
    float v = 0.f;
    if (row < 129)       v = note_W[row * 128 + k];
    else if (row == 129) v = dur_W[k];
    Wn[i] = (f16)v;
}

// ---------------------------------------------------------------------------
__global__ __launch_bounds__(512, 2) void lstm2_k(const float* __restrict__ x,
                                                  const int* __restrict__ lengths,
                                                  const float* __restrict__ W_ih,
                                                  const float* __restrict__ W_hh,
                                                  float* __restrict__ out) {
    // h double buffer: 8 batch rows x 128 cols, padded to 136 f16 (272B row
    // stride -> A-frag reads spread perfectly across banks).
    __shared__ __align__(16) f16  h_sh[2][8][136];
    __shared__ __align__(16) float xs[128][8][2];   // x chunk: 128 steps

    const int tid = threadIdx.x;
    const int g   = blockIdx.x;        // 0..31, batches g*8..g*8+7
    const int w   = tid >> 6;          // wave 0..7
    const int l   = tid & 63;
    const int p   = l & 15;
    const int q   = l >> 4;
    const int j   = 16 * w + p;        // hidden column 0..127
    const bool qlow = (q < 2);
    // this lane's two (batch) rows: q=0->{0,1}, q=1->{4,5}, q=2->{2,3}, q=3->{6,7}
    const int bb0 = 4 * (q & 1) + (qlow ? 0 : 2);
    const int bb1 = bb0 + 1;
    const int bg0 = g * 8 + bb0, bg1 = g * 8 + bb1;

    // --- static B-fragments: W_hh row c = 128*gate + j, k-slice 8 per (kt,q)
    f16x8 Bf[4][4];
    float wxx[4], wxy[4];
#pragma unroll
    for (int gi = 0; gi < 4; gi++) {
        const int c = 128 * gi + j;
        const float* wr = W_hh + (size_t)c * H_ + 8 * q;
#pragma unroll
        for (int kt = 0; kt < 4; kt++) {
            float4 v1 = *(const float4*)(wr + 32 * kt);
            float4 v2 = *(const float4*)(wr + 32 * kt + 4);
            f16x8 f;
            f[0] = (f16)v1.x; f[1] = (f16)v1.y; f[2] = (f16)v1.z; f[3] = (f16)v1.w;
            f[4] = (f16)v2.x; f[5] = (f16)v2.y; f[6] = (f16)v2.z; f[7] = (f16)v2.w;
            Bf[gi][kt] = f;
        }
        wxx[gi] = W_ih[2 * c];
        wxy[gi] = W_ih[2 * c + 1];
    }
    const int len0 = lengths[bg0];
    const int len1 = lengths[bg1];
    int maxlen = 0;
    for (int k = 0; k < 8; k++) maxlen = max(maxlen, lengths[g * 8 + k]);

    // zero both h buffers (incl. padding)
    for (int i = tid; i < 2 * 8 * 136; i += 512) ((f16*)h_sh)[i] = (f16)0.f;

    float c0 = 0.f, c1 = 0.f, h0 = 0.f, h1 = 0.f;
    const int arow = p & 7;            // A row replication: rows 8..15 = 0..7
    __syncthreads();

    for (int t = 0; t < maxlen; t++) {
        if ((t & 127) == 0) {
            // refill x chunk [t, t+128): thread i loads 1 float4 (2 steps) of
            // batch (i>>6). Prior chunk reads drained at last step's barrier.
            const int bb = tid >> 6, idx = tid & 63;
            float4 v = *(const float4*)(x + (size_t)(g * 8 + bb) * (T_ * 2)
                                          + (size_t)(t + 2 * idx) * 2);
            *(float2*)&xs[2 * idx][bb][0]     = make_float2(v.x, v.y);
            *(float2*)&xs[2 * idx + 1][bb][0] = make_float2(v.z, v.w);
            __syncthreads();
        }
        const int cur = t & 1;

        // A-fragments from h LDS (rows replicated via &7)
        f16x8 Af[4];
#pragma unroll
        for (int kt = 0; kt < 4; kt++)
            Af[kt] = *(const f16x8*)(&h_sh[cur][arow][32 * kt + 8 * q]);

        // x pair for this lane's two batches (16B contiguous)
        float4 xv = *(const float4*)(&xs[t & 127][bb0][0]);

        // MFMA: 4 gate-tiles x 4 k-tiles
        f32x4 acc[4];
#pragma unroll
        for (int gi = 0; gi < 4; gi++) acc[gi] = f32x4{0.f, 0.f, 0.f, 0.f};
#pragma unroll
        for (int kt = 0; kt < 4; kt++) {
#pragma unroll
            for (int gi = 0; gi < 4; gi++)
                acc[gi] = __builtin_amdgcn_mfma_f32_16x16x32_f16(
                    Af[kt], Bf[gi][kt], acc[gi], 0, 0, 0);
        }

        // select this lane's two rows out of its 4 acc regs
        float ga[4], gb[4];
#pragma unroll
        for (int gi = 0; gi < 4; gi++) {
            ga[gi] = qlow ? acc[gi][0] : acc[gi][2];
            gb[gi] = qlow ? acc[gi][1] : acc[gi][3];
        }
        // add input projection (W_ih . x_t)
#pragma unroll
        for (int gi = 0; gi < 4; gi++) {
            ga[gi] += __builtin_fmaf(wxy[gi], xv.y, wxx[gi] * xv.x);
            gb[gi] += __builtin_fmaf(wxy[gi], xv.w, wxx[gi] * xv.z);
        }

        // cell updates (i,f,g,o order)
        {
            float ig = sigmoid_f(ga[0]), fg = sigmoid_f(ga[1]);
            float gg = tanh_f(ga[2]),    og = sigmoid_f(ga[3]);
            float cn = __builtin_fmaf(fg, c0, ig * gg);
            float hn = og * tanh_f(fminf(fmaxf(cn, -15.f), 15.f));
            bool m = (t < len0);
            c0 = m ? cn : c0;
            h0 = m ? hn : h0;
            h_sh[cur ^ 1][bb0][j] = (f16)h0;
            if (m) hs_row(out, bg0 * T_ + t)[j] = (f16)h0;
        }
        {
            float ig = sigmoid_f(gb[0]), fg = sigmoid_f(gb[1]);
            float gg = tanh_f(gb[2]),    og = sigmoid_f(gb[3]);
            float cn = __builtin_fmaf(fg, c1, ig * gg);
            float hn = og * tanh_f(fminf(fmaxf(cn, -15.f), 15.f));
            bool m = (t < len1);
            c1 = m ? cn : c1;
            h1 = m ? hn : h1;
            h_sh[cur ^ 1][bb1][j] = (f16)h1;
            if (m) hs_row(out, bg1 * T_ + t)[j] = (f16)h1;
        }

        // drain LDS only; global hs stores remain in flight
        asm volatile("s_waitcnt lgkmcnt(0)" ::: "memory");
        __builtin_amdgcn_sched_barrier(0);
        __builtin_amdgcn_s_barrier();
        __builtin_amdgcn_sched_barrier(0);
    }

    out[HT_BASE + (size_t)bg0 * H_ + j] = h0;
    out[HT_BASE + (size_t)bg1 * H_ + j] = h1;
    out[CT_BASE + (size_t)bg0 * H_ + j] = c0;
    out[CT_BASE + (size_t)bg1 * H_ + j] = c1;
}

// ---------------------------------------------------------------------------
// Projection GEMM: C[bt, n] = hs[bt,:] . Wn[n,:] + bias, masked by t<len.
__global__ __launch_bounds__(256) void proj_k(const int* __restrict__ lengths,
                                              const f16* __restrict__ Wn,
                                              const float* __restrict__ note_b,
                                              const float* __restrict__ dur_b,
                                              float* __restrict__ out) {
    __shared__ __align__(16) f16 wn_sh[144 * 136];

    const int tid = threadIdx.x;
    {
        unsigned int* dst = (unsigned int*)wn_sh;
        const unsigned int* src = (const unsigned int*)Wn;
        for (int w = tid; w < 144 * 64; w += 256) {
            int row = w >> 6, cw = w & 63;
            dst[row * 68 + cw] = src[w];
        }
    }
    __syncthreads();

    const int wv = tid >> 6;
    const int l = tid & 63;
    const int tile = blockIdx.x * 4 + wv;
    const int bt0 = tile * 16;
    const int b = bt0 >> 11;
    const int t0 = bt0 & 2047;
    const int len = lengths[b];
    const int r16 = l & 15, q = l >> 4;

    f32x4 acc[9];
#pragma unroll
    for (int nf = 0; nf < 9; nf++) acc[nf] = f32x4{0.f, 0.f, 0.f, 0.f};

    const bool live = (t0 < len);
    if (live) {
        f16x8 a[4];
        {
            const f16* ar = hs_row(out, bt0 + r16);
#pragma unroll
            for (int kk = 0; kk < 4; kk++)
                a[kk] = *(const f16x8*)(ar + kk * 32 + q * 8);
        }
#pragma unroll
        for (int nf = 0; nf < 9; nf++) {
            const f16* brow = wn_sh + (nf * 16 + r16) * 136 + q * 8;
#pragma unroll
            for (int kk = 0; kk < 4; kk++) {
                f16x8 bb = *(const f16x8*)(brow + kk * 32);
                acc[nf] = __builtin_amdgcn_mfma_f32_16x16x32_f16(a[kk], bb, acc[nf], 0, 0, 0);
            }
        }
    }

#pragma unroll
    for (int nf = 0; nf < 9; nf++) {
        int col = nf * 16 + r16;
        float bias = 0.f;
        if (col < 129)       bias = note_b[col];
        else if (col == 129) bias = dur_b[0];
#pragma unroll
        for (int r = 0; r < 4; r++) {
            int rowbt = bt0 + q * 4 + r;
            int t = t0 + q * 4 + r;
            float v = (t < len) ? (acc[nf][r] + bias) : 0.f;
            if (col < 129)
                out[(size_t)rowbt * P_ + col] = v;
            else if (col == 129)
                out[DUR_BASE + rowbt] = v;
        }
    }
}

// ---------------------------------------------------------------------------
extern "C" void kernel_launch(void* const* d_in, const int* in_sizes, int n_in,
                              void* d_out, int out_size, void* d_ws, size_t ws_size,
                              hipStream_t stream) {
    const float* x       = (const float*)d_in[0];
    const int*   lengths = (const int*)d_in[1];
    const float* W_ih    = (const float*)d_in[2];
    const float* W_hh    = (const float*)d_in[3];
    const float* note_W  = (const float*)d_in[4];
    const float* note_b  = (const float*)d_in[5];
    const float* dur_W   = (const float*)d_in[6];
    const float* dur_b   = (const float*)d_in[7];
    float* out = (float*)d_out;
    f16* Wn = (f16*)d_ws;

    prep_k<<<72, 256, 0, stream>>>(note_W, dur_W, Wn);
    lstm2_k<<<32, 512, 0, stream>>>(x, lengths, W_ih, W_hh, out);
    proj_k<<<(B_ * T_) / 64, 256, 0, stream>>>(lengths, Wn, note_b, dur_b, out);
}

// Round 8
// 1066.294 us; speedup vs baseline: 1.5146x; 1.5146x over previous
//
#include <hip/hip_runtime.h>

// ---------------------------------------------------------------------------
// MusicLSTM: B=256, T=2048, I=2, H=128 (4H=512 gates), P=129 pitches.
//   prep_k  : note_W+dur_W -> f16 Wn[144][128] in ws
//   lstm3_k : 1 WG (512 thr, 8 waves) per batch. Wall time = maxlen x
//             per-step critical path, so this design minimizes the path:
//             gates[512] = W_hh . h via MFMA 16x16x32 with h BROADCAST as A
//             (rows replicated; all lanes of a q-group read the same 16B ->
//             conflict-free). Wave w owns n-tiles {w,w+8,w+16,w+24}; lane
//             (p,q) owns column j=16w+p, gates c=j+128*tt land in acc[tt][*]
//             (all 4 m-rows identical). ONE cell update per lane (10 trans,
//             not 4x redundant), no cross-lane reduce at all. One raw
//             s_barrier per step (lgkm-only drain; global hs stores stay in
//             flight). h double-buffered in LDS; x staged in 128-step chunks.
//   proj_k  : MFMA f16 GEMM over hs -> note/dur logits, masked rows zeroed.
// Fragment layout conventions (verified by the passing proj_k):
//   A: lane l holds A[m=l&15][k=32*kt+8*(l>>4)+e], e=0..7
//   B: lane l holds B[n=l&15][k=32*kt+8*(l>>4)+e]
//   D: lane l reg r holds D[m=(l>>4)*4+r][n=l&15]
// ---------------------------------------------------------------------------

typedef _Float16 f16;
typedef _Float16 f16x8 __attribute__((ext_vector_type(8)));
typedef float    f32x4 __attribute__((ext_vector_type(4)));

#define B_  256
#define T_  2048
#define H_  128
#define P_  129

static constexpr size_t NOTE_N   = (size_t)B_ * T_ * P_;
static constexpr size_t DUR_BASE = NOTE_N;
static constexpr size_t HT_BASE  = DUR_BASE + (size_t)B_ * T_;
static constexpr size_t CT_BASE  = HT_BASE + (size_t)B_ * H_;

#if defined(__has_builtin)
#if __has_builtin(__builtin_amdgcn_exp2f)
#define EXP2F(x) __builtin_amdgcn_exp2f(x)
#endif
#endif
#ifndef EXP2F
#define EXP2F(x) __expf((x) * 0.6931471805599453f)
#endif

__device__ __forceinline__ float fast_rcp(float x) { return __builtin_amdgcn_rcpf(x); }

__device__ __forceinline__ float sigmoid_f(float x) {
    float e = EXP2F(-1.44269504f * x);
    return fast_rcp(1.f + e);
}
__device__ __forceinline__ float tanh_f(float x) {
    float e = EXP2F(2.885390082f * x);
    return (e - 1.f) * fast_rcp(e + 1.f);
}

// hs row bt lives at the front of note row bt, rounded up to 16B alignment.
__device__ __forceinline__ f16* hs_row(float* out, int bt) {
    size_t byteoff = ((size_t)bt * (P_ * 4) + 15) & ~(size_t)15;
    return (f16*)((char*)out + byteoff);
}

// ---------------------------------------------------------------------------
__global__ __launch_bounds__(256) void prep_k(const float* __restrict__ note_W,
                                              const float* __restrict__ dur_W,
                                              f16* __restrict__ Wn) {
    int i = threadIdx.x + blockIdx.x * 256;
    if (i >= 144 * 128) return;
    int row = i >> 7, k = i & 127;
    float v = 0.f;
    if (row < 129)       v = note_W[row * 128 + k];
    else if (row == 129) v = dur_W[k];
    Wn[i] = (f16)v;
}

// ---------------------------------------------------------------------------
__global__ __launch_bounds__(512, 2) void lstm3_k(const float* __restrict__ x,
                                                  const int* __restrict__ lengths,
                                                  const float* __restrict__ W_ih,
                                                  const float* __restrict__ W_hh,
                                                  float* __restrict__ out) {
    __shared__ __align__(16) f16 h_sh[2][H_];   // double-buffered h (512 B)
    __shared__ __align__(8) float2 xs[128];     // x chunk: 128 steps (1 KB)

    const int tid = threadIdx.x;
    const int b = blockIdx.x;
    const int w = tid >> 6;       // wave 0..7
    const int l = tid & 63;
    const int p = l & 15;
    const int q = l >> 4;
    const int j = 16 * w + p;     // this lane's hidden column

    // B-fragments: gate rows c = j + 128*tt (tt = i,f,g,o), k-slice 8q..8q+7
    f16x8 Bf[4][4];
    float wxx[4], wxy[4];
#pragma unroll
    for (int tt = 0; tt < 4; tt++) {
        const int c = j + 128 * tt;
        const float* wr = W_hh + (size_t)c * H_ + 8 * q;
#pragma unroll
        for (int kt = 0; kt < 4; kt++) {
            float4 v1 = *(const float4*)(wr + 32 * kt);
            float4 v2 = *(const float4*)(wr + 32 * kt + 4);
            f16x8 f;
            f[0] = (f16)v1.x; f[1] = (f16)v1.y; f[2] = (f16)v1.z; f[3] = (f16)v1.w;
            f[4] = (f16)v2.x; f[5] = (f16)v2.y; f[6] = (f16)v2.z; f[7] = (f16)v2.w;
            Bf[tt][kt] = f;
        }
        wxx[tt] = W_ih[2 * c];
        wxy[tt] = W_ih[2 * c + 1];
    }
    const int len = lengths[b];
    if (tid < 2 * H_) ((f16*)h_sh)[tid] = (f16)0.f;

    float c_reg = 0.f, h_reg = 0.f;
    __syncthreads();

    for (int t = 0; t < len; t++) {
        if ((t & 127) == 0) {
            // refill x chunk [t, t+128) (full-drain barrier, amortized /128)
            if (tid < 128)
                xs[tid] = *(const float2*)(x + (size_t)b * T_ * 2 + (size_t)(t + tid) * 2);
            __syncthreads();
        }
        const int cur = t & 1;

        // A-fragments: h broadcast (same 16B for all lanes of a q-group)
        f16x8 Af[4];
#pragma unroll
        for (int kt = 0; kt < 4; kt++)
            Af[kt] = *(const f16x8*)(&h_sh[cur][32 * kt + 8 * q]);

        f32x4 acc[4];
#pragma unroll
        for (int tt = 0; tt < 4; tt++) acc[tt] = f32x4{0.f, 0.f, 0.f, 0.f};
#pragma unroll
        for (int kt = 0; kt < 4; kt++) {
#pragma unroll
            for (int tt = 0; tt < 4; tt++)
                acc[tt] = __builtin_amdgcn_mfma_f32_16x16x32_f16(
                    Af[kt], Bf[tt][kt], acc[tt], 0, 0, 0);
        }

        const float2 xv = xs[t & 127];
        float g0 = acc[0][0] + __builtin_fmaf(wxy[0], xv.y, wxx[0] * xv.x);
        float g1 = acc[1][0] + __builtin_fmaf(wxy[1], xv.y, wxx[1] * xv.x);
        float g2 = acc[2][0] + __builtin_fmaf(wxy[2], xv.y, wxx[2] * xv.x);
        float g3 = acc[3][0] + __builtin_fmaf(wxy[3], xv.y, wxx[3] * xv.x);

        const float ig = sigmoid_f(g0);
        const float fg = sigmoid_f(g1);
        const float gg = tanh_f(g2);
        const float og = sigmoid_f(g3);
        c_reg = __builtin_fmaf(fg, c_reg, ig * gg);
        h_reg = og * tanh_f(fminf(fmaxf(c_reg, -15.f), 15.f));

        if (q == 0) {
            const f16 h16 = (f16)h_reg;
            h_sh[cur ^ 1][j] = h16;               // LDS (lgkm)
            hs_row(out, b * T_ + t)[j] = h16;     // global, stays in flight
        }
        // drain LDS only; global hs stores remain outstanding
        asm volatile("s_waitcnt lgkmcnt(0)" ::: "memory");
        __builtin_amdgcn_sched_barrier(0);
        __builtin_amdgcn_s_barrier();
        __builtin_amdgcn_sched_barrier(0);
    }

    if (q == 0) {
        out[HT_BASE + (size_t)b * H_ + j] = h_reg;
        out[CT_BASE + (size_t)b * H_ + j] = c_reg;
    }
}

// ---------------------------------------------------------------------------
// Projection GEMM: C[bt, n] = hs[bt,:] . Wn[n,:] + bias, masked by t<len.
__global__ __launch_bounds__(256) void proj_k(const int* __restrict__ lengths,
                                              const f16* __restrict__ Wn,
                                              const float* __restrict__ note_b,
                                              const float* __restrict__ dur_b,
                                              float* __restrict__ out) {
    __shared__ __align__(16) f16 wn_sh[144 * 136];

    const int tid = threadIdx.x;
    {
        unsigned int* dst = (unsigned int*)wn_sh;
        const unsigned int* src = (const unsigned int*)Wn;
        for (int w = tid; w < 144 * 64; w += 256) {
            int row = w >> 6, cw = w & 63;
            dst[row * 68 + cw] = src[w];
        }
    }
    __syncthreads();

    const int wv = tid >> 6;
    const int l = tid & 63;
    const int tile = blockIdx.x * 4 + wv;
    const int bt0 = tile * 16;
    const int b = bt0 >> 11;
    const int t0 = bt0 & 2047;
    const int len = lengths[b];
    const int r16 = l & 15, q = l >> 4;

    f32x4 acc[9];
#pragma unroll
    for (int nf = 0; nf < 9; nf++) acc[nf] = f32x4{0.f, 0.f, 0.f, 0.f};

    const bool live = (t0 < len);
    if (live) {
        f16x8 a[4];
        {
            const f16* ar = hs_row(out, bt0 + r16);
#pragma unroll
            for (int kk = 0; kk < 4; kk++)
                a[kk] = *(const f16x8*)(ar + kk * 32 + q * 8);
        }
#pragma unroll
        for (int nf = 0; nf < 9; nf++) {
            const f16* brow = wn_sh + (nf * 16 + r16) * 136 + q * 8;
#pragma unroll
            for (int kk = 0; kk < 4; kk++) {
                f16x8 bb = *(const f16x8*)(brow + kk * 32);
                acc[nf] = __builtin_amdgcn_mfma_f32_16x16x32_f16(a[kk], bb, acc[nf], 0, 0, 0);
            }
        }
    }

#pragma unroll
    for (int nf = 0; nf < 9; nf++) {
        int col = nf * 16 + r16;
        float bias = 0.f;
        if (col < 129)       bias = note_b[col];
        else if (col == 129) bias = dur_b[0];
#pragma unroll
        for (int r = 0; r < 4; r++) {
            int rowbt = bt0 + q * 4 + r;
            int t = t0 + q * 4 + r;
            float v = (t < len) ? (acc[nf][r] + bias) : 0.f;
            if (col < 129)
                out[(size_t)rowbt * P_ + col] = v;
            else if (col == 129)
                out[DUR_BASE + rowbt] = v;
        }
    }
}

// ---------------------------------------------------------------------------
extern "C" void kernel_launch(void* const* d_in, const int* in_sizes, int n_in,
                              void* d_out, int out_size, void* d_ws, size_t ws_size,
                              hipStream_t stream) {
    const float* x       = (const float*)d_in[0];
    const int*   lengths = (const int*)d_in[1];
    const float* W_ih    = (const float*)d_in[2];
    const float* W_hh    = (const float*)d_in[3];
    const float* note_W  = (const float*)d_in[4];
    const float* note_b  = (const float*)d_in[5];
    const float* dur_W   = (const float*)d_in[6];
    const float* dur_b   = (const float*)d_in[7];
    float* out = (float*)d_out;
    f16* Wn = (f16*)d_ws;

    prep_k<<<72, 256, 0, stream>>>(note_W, dur_W, Wn);
    lstm3_k<<<B_, 512, 0, stream>>>(x, lengths, W_ih, W_hh, out);
    proj_k<<<(B_ * T_) / 64, 256, 0, stream>>>(lengths, Wn, note_b, dur_b, out);
}